// Round 8
// baseline (772.180 us; speedup 1.0000x reference)
//
#include <hip/hip_runtime.h>

#define NC 91
#define NB 32
#define HW (1024 * 1024)

#define THREADS 256
#define PPT 64                          // pixels per thread
#define PIX_PER_BLOCK (THREADS * PPT)   // 16384
#define CHUNKS (HW / PIX_PER_BLOCK)     // 64 blocks per batch
#define NCOPY 8                         // LDS histogram sub-copies (copy = lane&7)
#define TCOPY 2                         // global histogram sub-copies (per wave pair)

// Round-8: PIPE SPLIT. Rounds 0-6 established a ~100 us floor for any
// all-LDS histogram: >=2 LDS lane-updates/pixel at ~1 lane/cyc (atomic) or
// row-coalesce-limited (plain). Round 7 showed the remaining ~175 us of
// dur_us is fixed harness overhead (constant across 2 vs 3 dispatches and
// kernel times 102..527 us) — so the hist kernel is the only lever.
//
// Split the 2 updates/pixel across two INDEPENDENT pipes:
//   x-update -> LDS atomic, 8-copy block histogram (round-4 structure,
//               now 1.01 lane-updates/px -> ~55 us of DS traffic)
//   t-update -> global_atomic_add into a per-block-PRIVATE 2-copy region
//               (12 cachelines/block, L2-resident in the local XCD,
//               fire-and-forget: no return value -> no vmcnt wait)
//   x==t     -> rare LDS atomic for intersection (~1/91 of lanes)
// The DS and TCC pipes run concurrently; expected hist ~= max(DS ~55,
// TCC ~?, HBM ~42) us. No fences, no completion counters (round-7 lesson).

__global__ __launch_bounds__(256, 8) void hist_kernel(const int* __restrict__ x,
                                                      const int* __restrict__ t,
                                                      int* __restrict__ g_hist,
                                                      int* __restrict__ g_inter,
                                                      int* __restrict__ g_t) {
    __shared__ int s_h[NCOPY * NC];   // 728 words = 2912 B
    __shared__ int s_inter[NC];

    const int tid = threadIdx.x;
    for (int j = tid; j < NCOPY * NC; j += THREADS) s_h[j] = 0;
    if (tid < NC) s_inter[tid] = 0;
    __syncthreads();

    int* hp = &s_h[(tid & 7) * NC];

    const int b = blockIdx.y;
    const int blin = b * CHUNKS + blockIdx.x;
    // per-block-private global region; copy chosen by wave pair (tid>>7)
    int* __restrict__ gt = g_t + ((long)blin * TCOPY + (tid >> 7)) * NC;

    const long base = (long)b * HW + (long)blockIdx.x * PIX_PER_BLOCK;
    const int4* __restrict__ x4 = (const int4*)(x + base);
    const int4* __restrict__ t4 = (const int4*)(t + base);

    const int n = PPT / 4;   // 16 iterations, 4 pixels each
    int4 xv0 = x4[tid],           tv0 = t4[tid];
    int4 xv1 = x4[THREADS + tid], tv1 = t4[THREADS + tid];

    for (int i = 0; i < n; ++i) {
        const int pf = (i + 2 < n) ? (i + 2) : (n - 1);   // clamped prefetch
        int4 xn = x4[pf * THREADS + tid];
        int4 tn = t4[pf * THREADS + tid];

        // x -> LDS pipe, t -> TCC pipe, intersection -> rare LDS atomic
        atomicAdd(&hp[xv0.x], 1);
        atomicAdd(&gt[tv0.x], 1);
        if (xv0.x == tv0.x) atomicAdd(&s_inter[xv0.x], 1);

        atomicAdd(&hp[xv0.y], 1);
        atomicAdd(&gt[tv0.y], 1);
        if (xv0.y == tv0.y) atomicAdd(&s_inter[xv0.y], 1);

        atomicAdd(&hp[xv0.z], 1);
        atomicAdd(&gt[tv0.z], 1);
        if (xv0.z == tv0.z) atomicAdd(&s_inter[xv0.z], 1);

        atomicAdd(&hp[xv0.w], 1);
        atomicAdd(&gt[tv0.w], 1);
        if (xv0.w == tv0.w) atomicAdd(&s_inter[xv0.w], 1);

        xv0 = xv1; tv0 = tv1;
        xv1 = xn;  tv1 = tn;
    }
    __syncthreads();

    // Epilogue: fold 8 LDS copies (x-counts), one global atomic per class.
    if (tid < NC) {
        int sum = 0;
#pragma unroll
        for (int k = 0; k < NCOPY; ++k) sum += s_h[k * NC + tid];
        if (sum) atomicAdd(&g_hist[b * NC + tid], sum);   // cnt_x
        const int in = s_inter[tid];
        if (in)  atomicAdd(&g_inter[b * NC + tid], in);
    }
}

__global__ __launch_bounds__(64) void finalize_kernel(const int* __restrict__ g_hist,
                                                      const int* __restrict__ g_inter,
                                                      const int* __restrict__ g_t,
                                                      const float* __restrict__ smooth,
                                                      float* __restrict__ out) {
    const int b = blockIdx.x;
    const int lane = threadIdx.x;  // 0..63
    const float s = smooth[0];
    float acc = 0.0f;
    for (int c = lane; c < NC; c += 64) {
        int cx = g_hist[b * NC + c];            // x-counts (LDS pipe)
        int ct = 0;                             // t-counts (TCC pipe)
        const int* gt = g_t + (long)b * CHUNKS * TCOPY * NC + c;
        for (int k = 0; k < CHUNKS * TCOPY; ++k)
            ct += gt[(long)k * NC];
        int in = g_inter[b * NC + c];
        // union = cnt_x + cnt_t - inter
        acc += ((float)in + s) / ((float)(cx + ct - in) + s);
    }
#pragma unroll
    for (int off = 32; off > 0; off >>= 1)
        acc += __shfl_down(acc, off, 64);
    if (lane == 0) out[b] = acc / (float)NC;
}

extern "C" void kernel_launch(void* const* d_in, const int* in_sizes, int n_in,
                              void* d_out, int out_size, void* d_ws, size_t ws_size,
                              hipStream_t stream) {
    const int* x = (const int*)d_in[0];
    const int* t = (const int*)d_in[1];
    const float* smooth = (const float*)d_in[2];
    float* out = (float*)d_out;

    int* g_hist = (int*)d_ws;                         // NB*NC
    int* g_inter = g_hist + NB * NC;                  // NB*NC
    int* g_t = g_inter + NB * NC;                     // NB*CHUNKS*TCOPY*NC

    const size_t ws_ints = (size_t)2 * NB * NC + (size_t)NB * CHUNKS * TCOPY * NC;
    hipMemsetAsync(d_ws, 0, ws_ints * sizeof(int), stream);   // ~1.5 MB

    dim3 grid(CHUNKS, NB);  // 64 x 32 = 2048 blocks
    hist_kernel<<<grid, THREADS, 0, stream>>>(x, t, g_hist, g_inter, g_t);
    finalize_kernel<<<NB, 64, 0, stream>>>(g_hist, g_inter, g_t, smooth, out);
}

// Round 9
// 281.559 us; speedup vs baseline: 2.7425x; 2.7425x over previous
//
#include <hip/hip_runtime.h>

#define NC 91
#define NB 32
#define HW (1024 * 1024)

#define THREADS 256
#define PPT 64                          // pixels per thread
#define PIX_PER_BLOCK (THREADS * PPT)   // 16384
#define CHUNKS (HW / PIX_PER_BLOCK)     // 64 blocks per batch
#define RSTR 92                         // row stride (words): 368 B, 16B-aligned

// Round-9: PAIR HISTOGRAM — one LDS update per pixel.
// cnt_x, cnt_t, inter are all marginals of the joint histogram P[x][t]:
//   cnt_x[c] = sum_t P[c][t], cnt_t[c] = sum_x P[x][c], inter[c] = P[c][c].
// So one ds_add per pixel into P (bin = x*92 + t) replaces the 2 updates/px
// of every previous round. DS model from rounds 0-8: LDS atomics retire
// ~1 distinct address/cyc/CU, so halving update count halves the ~100 us
// DS wall. Collisions vanish too (64 lanes into 8372 bins) and the x==t
// compare/branch leaves the hot loop (intersection = diagonal).
// 33.5 KB LDS -> 4 blocks/CU; ds_add has no return value -> no lgkmcnt
// waits; depth-2 clamped prefetch as in round 4 (unchanged, proven).

__global__ __launch_bounds__(256, 4) void hist_kernel(const int* __restrict__ x,
                                                      const int* __restrict__ t,
                                                      int* __restrict__ g_cx,
                                                      int* __restrict__ g_ct,
                                                      int* __restrict__ g_in) {
    __shared__ __align__(16) int s_pair[NC * RSTR];   // 8372 words = 33,488 B

    const int tid = threadIdx.x;
    for (int j = tid; j < NC * RSTR; j += THREADS) s_pair[j] = 0;
    __syncthreads();

    const int b = blockIdx.y;
    const long base = (long)b * HW + (long)blockIdx.x * PIX_PER_BLOCK;
    const int4* __restrict__ x4 = (const int4*)(x + base);
    const int4* __restrict__ t4 = (const int4*)(t + base);

    const int n = PPT / 4;   // 16 iterations, 4 pixels each
    int4 xv0 = x4[tid],           tv0 = t4[tid];
    int4 xv1 = x4[THREADS + tid], tv1 = t4[THREADS + tid];

    for (int i = 0; i < n; ++i) {
        const int pf = (i + 2 < n) ? (i + 2) : (n - 1);   // clamped prefetch
        int4 xn = x4[pf * THREADS + tid];
        int4 tn = t4[pf * THREADS + tid];

        // one fire-and-forget ds_add per pixel
        atomicAdd(&s_pair[xv0.x * RSTR + tv0.x], 1);
        atomicAdd(&s_pair[xv0.y * RSTR + tv0.y], 1);
        atomicAdd(&s_pair[xv0.z * RSTR + tv0.z], 1);
        atomicAdd(&s_pair[xv0.w * RSTR + tv0.w], 1);

        xv0 = xv1; tv0 = tv1;
        xv1 = xn;  tv1 = tn;
    }
    __syncthreads();

    // Epilogue: fold the joint histogram into its three marginals.
    // threads 0..90: column sums (cnt_t) + diagonal (inter).
    //   Per wave-instr (fixed xx), lane addrs are contiguous -> fast.
    if (tid < NC) {
        int ct = 0;
        for (int xx = 0; xx < NC; ++xx) ct += s_pair[xx * RSTR + tid];
        if (ct) atomicAdd(&g_ct[b * NC + tid], ct);
        const int dg = s_pair[tid * RSTR + tid];
        if (dg) atomicAdd(&g_in[b * NC + tid], dg);
    }
    // threads 128..218: row sums (cnt_x) via int4 (368-byte stride, 16B-aligned;
    //   the single pad word is always zero, harmless to include).
    else if (tid >= 128 && tid < 128 + NC) {
        const int c = tid - 128;
        const int4* row = (const int4*)&s_pair[c * RSTR];
        int cx = 0;
#pragma unroll
        for (int j = 0; j < RSTR / 4; ++j) {
            int4 v = row[j];
            cx += v.x + v.y + v.z + v.w;
        }
        if (cx) atomicAdd(&g_cx[b * NC + c], cx);
    }
}

__global__ __launch_bounds__(64) void finalize_kernel(const int* __restrict__ g_cx,
                                                      const int* __restrict__ g_ct,
                                                      const int* __restrict__ g_in,
                                                      const float* __restrict__ smooth,
                                                      float* __restrict__ out) {
    const int b = blockIdx.x;
    const int lane = threadIdx.x;  // 0..63
    const float s = smooth[0];
    float acc = 0.0f;
    for (int c = lane; c < NC; c += 64) {
        const float in = (float)g_in[b * NC + c];
        const float un = (float)(g_cx[b * NC + c] + g_ct[b * NC + c]) - in;
        acc += (in + s) / (un + s);
    }
#pragma unroll
    for (int off = 32; off > 0; off >>= 1)
        acc += __shfl_down(acc, off, 64);
    if (lane == 0) out[b] = acc / (float)NC;
}

extern "C" void kernel_launch(void* const* d_in, const int* in_sizes, int n_in,
                              void* d_out, int out_size, void* d_ws, size_t ws_size,
                              hipStream_t stream) {
    const int* x = (const int*)d_in[0];
    const int* t = (const int*)d_in[1];
    const float* smooth = (const float*)d_in[2];
    float* out = (float*)d_out;

    int* g_cx = (int*)d_ws;                   // NB*NC
    int* g_ct = g_cx + NB * NC;               // NB*NC
    int* g_in = g_ct + NB * NC;               // NB*NC

    hipMemsetAsync(d_ws, 0, 3 * NB * NC * sizeof(int), stream);

    dim3 grid(CHUNKS, NB);  // 64 x 32 = 2048 blocks
    hist_kernel<<<grid, THREADS, 0, stream>>>(x, t, g_cx, g_ct, g_in);
    finalize_kernel<<<NB, 64, 0, stream>>>(g_cx, g_ct, g_in, smooth, out);
}